// Round 2
// baseline (223.889 us; speedup 1.0000x reference)
//
#include <hip/hip_runtime.h>
#include <hip/hip_bf16.h>
#include <stdint.h>

// BLSTMCell: gates = [x|hx] @ sign([W_ih|W_hh])^T + (b_ih+b_hh); LSTM pointwise.
// M=8192, N=2048 (4 gates x 512), K=1024. Inputs are fp32; to beat the 0.116
// absmax threshold we split x into hi+lo bf16 terms (residual ~2^-18) and run
// TWO bf16 MFMA passes (hi,lo) against each staged W chunk, one accumulator.
// ws: [0]=flag, +256 bias fp32[2048], +16384 Wsign bf16[2048x1024] (4 MB),
//     +16384+4MB: Xc2 bf16[8192 x 2048] ([hi(1024)|lo(1024)] per row, 32 MB).

typedef __attribute__((ext_vector_type(8))) short short8;
typedef __attribute__((ext_vector_type(4))) float floatx4;

#define B_DIM 8192
#define H_DIM 512

__device__ __forceinline__ float bf2f(uint16_t u) {
  return __uint_as_float(((uint32_t)u) << 16);
}
__device__ __forceinline__ uint16_t f2bf(float f) {
  uint32_t u = __float_as_uint(f);
  return (uint16_t)((u + 0x7FFFu + ((u >> 16) & 1u)) >> 16);
}
__device__ __forceinline__ float sigm(float x) { return 1.0f / (1.0f + __expf(-x)); }
__device__ __forceinline__ float tanh_f(float x) { return 2.0f / (1.0f + __expf(-2.0f * x)) - 1.0f; }

__device__ __forceinline__ void gld_lds16(const void* g, void* l) {
  __builtin_amdgcn_global_load_lds((const __attribute__((address_space(1))) char*)g,
                                   (__attribute__((address_space(3))) char*)l, 16, 0, 0);
}

// ---------------- detect dtype + combine biases (1 block, 256 threads) -------------
__global__ void detect_bias_kernel(const uint32_t* __restrict__ x_words,
                                   const void* __restrict__ b_ih, const void* __restrict__ b_hh,
                                   int* __restrict__ flag_ws, float* __restrict__ bias_out) {
  __shared__ int s_big;
  if (threadIdx.x == 0) s_big = 0;
  __syncthreads();
  // fp32 buffer: low 16 bits of dwords as bf16 have ~uniform exponents -> huge values.
  // genuine bf16 N(0,1)/uniform data: |v| < 64 always.
  uint32_t w = x_words[threadIdx.x];
  uint32_t e0 = (w >> 7) & 0xFFu;
  uint32_t e1 = (w >> 23) & 0xFFu;
  if (e0 > 0x85u || e1 > 0x85u) atomicOr(&s_big, 1);
  __syncthreads();
  const int isF32 = s_big;
  if (threadIdx.x == 0) *flag_ws = isF32;
  for (int i = threadIdx.x; i < 2048; i += 256) {
    float bi, bh;
    if (isF32) {
      bi = ((const float*)b_ih)[i];
      bh = ((const float*)b_hh)[i];
    } else {
      bi = bf2f(((const uint16_t*)b_ih)[i]);
      bh = bf2f(((const uint16_t*)b_hh)[i]);
    }
    bias_out[i] = bi + bh;
  }
}

// ---------------- prep ------------------------------------------------------------
// Xc2[m][k]: k<1024 -> hi bf16 of [x|hx][m][k]; k>=1024 -> lo bf16 (residual) of k-1024.
// Wsign[n][k] = sign as bf16 +-1, n = gate*512 + col.
__global__ void prep_kernel(const void* __restrict__ x, const void* __restrict__ hx,
                            const void* __restrict__ w_ih, const void* __restrict__ w_hh,
                            const int* __restrict__ flag_ws,
                            uint16_t* __restrict__ Xc, uint16_t* __restrict__ Wsign) {
  const int isF32 = *flag_ws;
  const int bid = blockIdx.x;
  if (bid < 8192) {  // Xc2: 8192*2048 elems, 8 per thread
    const long e = ((long)bid * 256 + threadIdx.x) * 8;
    const int m = (int)(e >> 11);
    const int k = (int)(e & 2047);
    const int klo = k & 1023;                  // position within [x|hx]
    const int isLo = k >> 10;                  // 0 = hi part, 1 = lo part
    const void* src = (klo < 512) ? x : hx;
    const long off = (long)m * 512 + (klo & 511);
    short8 ov;
    if (isF32) {
      const float* s = (const float*)src + off;
      if (!isLo) {
#pragma unroll
        for (int j = 0; j < 8; ++j) ov[j] = (short)f2bf(s[j]);
      } else {
#pragma unroll
        for (int j = 0; j < 8; ++j) {
          const float v = s[j];
          const float r = v - bf2f(f2bf(v));
          ov[j] = (short)f2bf(r);
        }
      }
    } else {
      if (!isLo) {
        ov = *(const short8*)((const uint16_t*)src + off);
      } else {
#pragma unroll
        for (int j = 0; j < 8; ++j) ov[j] = 0;
      }
    }
    *(short8*)(Xc + e) = ov;
  } else {  // Wsign: 2048*1024 elems
    const long e = ((long)(bid - 8192) * 256 + threadIdx.x) * 8;
    const int n = (int)(e >> 10);
    const int k = (int)(e & 1023);
    const void* src = (k < 512) ? w_ih : w_hh;
    const long off = (long)n * 512 + (k & 511);
    short8 ov;
    if (isF32) {
      const float* s = (const float*)src + off;
#pragma unroll
      for (int j = 0; j < 8; ++j) {
        float wv = s[j];
        ov[j] = (short)(uint16_t)(wv > 0.f ? 0x3F80u : (wv < 0.f ? 0xBF80u : 0u));
      }
    } else {
      const uint16_t* s = (const uint16_t*)src + off;
#pragma unroll
      for (int j = 0; j < 8; ++j) {
        uint16_t u = s[j];
        ov[j] = (short)(uint16_t)(((u & 0x7FFFu) == 0) ? 0u : ((u & 0x8000u) ? 0xBF80u : 0x3F80u));
      }
    }
    *(short8*)(Wsign + e) = ov;
  }
}

// ---------------- fused GEMM + LSTM epilogue ---------------------------------------
// grid (16, 64): x = n_blk (32 h-cols x 4 gates = 128 j-cols), y = m_blk (128 rows).
// j -> gate g = j&3, h-col c = c0 + (j>>2): all 4 gates of a column in ONE wave.
// K-loop: stage 64-k of A_hi, A_lo, B per iter; 64 MFMA per barrier, one acc.
__global__ __launch_bounds__(256) void blstm_gemm_kernel(
    const uint16_t* __restrict__ Xc, const uint16_t* __restrict__ Wsign,
    const float* __restrict__ bias, const void* __restrict__ cx,
    const int* __restrict__ flag_ws, void* __restrict__ out) {
  __shared__ alignas(16) char lds[49152];  // A_hi [0,16K) A_lo [16K,32K) B [32K,48K)
  const int tid = threadIdx.x;
  const int l = tid & 63, w = tid >> 6;
  const int lrow = l & 15, lq = l >> 4;
  const int wy = w >> 1, wx = w & 1;
  const int m0 = blockIdx.y * 128;
  const int c0 = blockIdx.x * 32;

  const uint16_t* aptr[4];  // hi pointers; lo = +1024 elements
  const uint16_t* bptr[4];
#pragma unroll
  for (int i = 0; i < 4; ++i) {
    const int id = w * 4 + i;
    const int grp = id >> 1, kh = id & 1;
    const int k = kh * 32 + lq * 8;
    aptr[i] = Xc + (long)(m0 + grp * 16 + lrow) * 2048 + k;
    const int j = grp * 16 + lrow;
    const int n = (j & 3) * 512 + c0 + (j >> 2);
    bptr[i] = Wsign + (long)n * 1024 + k;
  }

  floatx4 acc[4][4];
#pragma unroll
  for (int mt = 0; mt < 4; ++mt)
#pragma unroll
    for (int nt = 0; nt < 4; ++nt) acc[mt][nt] = (floatx4){0.f, 0.f, 0.f, 0.f};

  for (int ks = 0; ks < 16; ++ks) {
    __syncthreads();
#pragma unroll
    for (int i = 0; i < 4; ++i) {
      gld_lds16(aptr[i], lds + (w * 4 + i) * 1024);             // A hi
      gld_lds16(aptr[i] + 1024, lds + 16384 + (w * 4 + i) * 1024);  // A lo
      gld_lds16(bptr[i], lds + 32768 + (w * 4 + i) * 1024);     // B
      aptr[i] += 64;
      bptr[i] += 64;
    }
    __syncthreads();
#pragma unroll
    for (int kk = 0; kk < 2; ++kk) {
      short8 ah[4], al[4], b[4];
#pragma unroll
      for (int mt = 0; mt < 4; ++mt) {
        ah[mt] = *(const short8*)(lds + ((wy * 4 + mt) * 2 + kk) * 1024 + lq * 256 + lrow * 16);
        al[mt] = *(const short8*)(lds + 16384 + ((wy * 4 + mt) * 2 + kk) * 1024 + lq * 256 + lrow * 16);
      }
#pragma unroll
      for (int nt = 0; nt < 4; ++nt)
        b[nt] = *(const short8*)(lds + 32768 + ((wx * 4 + nt) * 2 + kk) * 1024 + lq * 256 + lrow * 16);
#pragma unroll
      for (int mt = 0; mt < 4; ++mt)
#pragma unroll
        for (int nt = 0; nt < 4; ++nt) {
          acc[mt][nt] = __builtin_amdgcn_mfma_f32_16x16x32_bf16(ah[mt], b[nt], acc[mt][nt], 0, 0, 0);
          acc[mt][nt] = __builtin_amdgcn_mfma_f32_16x16x32_bf16(al[mt], b[nt], acc[mt][nt], 0, 0, 0);
        }
    }
  }

  // ---------------- epilogue ----------------
  const int isF32 = *flag_ws;
  const long CYo = (long)B_DIM * H_DIM;
  float biasv[4];
#pragma unroll
  for (int nt = 0; nt < 4; ++nt) {
    const int c = c0 + wx * 16 + nt * 4 + (lrow >> 2);
    biasv[nt] = bias[(l & 3) * 512 + c];
  }
  float* outF = (float*)out;
  uint16_t* outB = (uint16_t*)out;
  const int base = l & ~3;
#pragma unroll
  for (int mt = 0; mt < 4; ++mt) {
#pragma unroll
    for (int nt = 0; nt < 4; ++nt) {
      const int c = c0 + wx * 16 + nt * 4 + (lrow >> 2);
      const int rowbase = m0 + wy * 64 + mt * 16 + lq * 4;
      float myi = 0.f, myf = 0.f, myg = 0.f, myo = 0.f;
#pragma unroll
      for (int r = 0; r < 4; ++r) {
        const float v = acc[mt][nt][r] + biasv[nt];
        const float vi = __shfl(v, base + 0, 64);
        const float vf = __shfl(v, base + 1, 64);
        const float vg = __shfl(v, base + 2, 64);
        const float vo = __shfl(v, base + 3, 64);
        if ((l & 3) == r) { myi = vi; myf = vf; myg = vg; myo = vo; }
      }
      const int row = rowbase + (l & 3);
      const long cidx = (long)row * H_DIM + c;
      float cxv;
      if (isF32) cxv = ((const float*)cx)[cidx];
      else       cxv = bf2f(((const uint16_t*)cx)[cidx]);
      const float ig = sigm(myi), fg = sigm(myf), og = sigm(myo);
      const float cg = tanh_f(myg);
      const float cy = fg * cxv + ig * cg;
      const float hy = og * tanh_f(cy);
      if (isF32) {
        outF[cidx] = hy;
        outF[CYo + cidx] = cy;
      } else {
        outB[cidx] = f2bf(hy);
        outB[CYo + cidx] = f2bf(cy);
      }
    }
  }
}

extern "C" void kernel_launch(void* const* d_in, const int* in_sizes, int n_in,
                              void* d_out, int out_size, void* d_ws, size_t ws_size,
                              hipStream_t stream) {
  const void* x = d_in[0];
  const void* hx = d_in[1];
  const void* cx = d_in[2];
  const void* W_ih = d_in[3];
  const void* W_hh = d_in[4];
  const void* b_ih = d_in[5];
  const void* b_hh = d_in[6];
  char* ws = (char*)d_ws;
  int* flag = (int*)ws;
  float* bias = (float*)(ws + 256);
  uint16_t* Wsign = (uint16_t*)(ws + 16384);
  uint16_t* Xc = (uint16_t*)(ws + 16384 + 4194304);

  detect_bias_kernel<<<1, 256, 0, stream>>>((const uint32_t*)x, b_ih, b_hh, flag, bias);
  prep_kernel<<<9216, 256, 0, stream>>>(x, hx, W_ih, W_hh, flag, Xc, Wsign);
  dim3 grid(16, 64);
  blstm_gemm_kernel<<<grid, 256, 0, stream>>>(Xc, Wsign, bias, cx, flag, d_out);
}

// Round 3
// 159.953 us; speedup vs baseline: 1.3997x; 1.3997x over previous
//
#include <hip/hip_runtime.h>
#include <hip/hip_bf16.h>
#include <stdint.h>

// BLSTMCell: gates = [x|hx] @ sign([W_ih|W_hh])^T + (b_ih+b_hh); LSTM pointwise.
// M=8192, N=2048 (4 gates x 512 cols), K=1024.
// Precision scheme: x quantized to int16 fixed point (scale 2^12, range +-8),
// split into hi/lo int8 bytes; two i8 MFMA passes with exact i32 accumulation:
//   gates = hi_acc * 2^-4 + lo_acc * 2^-12 + bias.  Quant err ~2.3e-3 std/gate.
// A and B are pre-packed in MFMA-fragment order (1KB tiles of 16 rows x 64 k,
// lane-contiguous) so gld_lds16 stages 1KB/wave-instr and LDS reads are
// conflict-free (addr = base + lane*16).
// ws: Xhi int8[8192x1024] (8MB) | Xlo (8MB) | Bp int8[2048x1024] (2MB) = 18MB.

typedef __attribute__((ext_vector_type(4))) int int4x;
typedef __attribute__((ext_vector_type(4))) float float4x;

#define B_DIM 8192
#define H_DIM 512

__device__ __forceinline__ float bf2f(uint16_t u) {
  return __uint_as_float(((uint32_t)u) << 16);
}
__device__ __forceinline__ uint16_t f2bf(float f) {
  uint32_t u = __float_as_uint(f);
  return (uint16_t)((u + 0x7FFFu + ((u >> 16) & 1u)) >> 16);
}
__device__ __forceinline__ float sigm(float x) { return 1.0f / (1.0f + __expf(-x)); }
__device__ __forceinline__ float tanh_f(float x) { return 2.0f / (1.0f + __expf(-2.0f * x)) - 1.0f; }

__device__ __forceinline__ void gld_lds16(const void* g, void* l) {
  __builtin_amdgcn_global_load_lds((const __attribute__((address_space(1))) char*)g,
                                   (__attribute__((address_space(3))) char*)l, 16, 0, 0);
}

// Wave-local dtype sniff: fp32 buffers have ~uniform exponent bits in their low
// halves -> reinterpreted-as-bf16 magnitude explodes; genuine bf16 N(0,1) never
// exceeds 2^6. Wave-uniform result (all waves check the same 64 dwords).
__device__ __forceinline__ int detect_f32(const void* x) {
  const int l = threadIdx.x & 63;
  uint32_t wrd = ((const uint32_t*)x)[l];
  uint32_t e0 = (wrd >> 7) & 0xFFu, e1 = (wrd >> 23) & 0xFFu;
  return __ballot(e0 > 0x85u || e1 > 0x85u) != 0ull;
}

// ---------------- prep: pack A (hi/lo int8) and B (sign int8) fragment-ordered ----
// X tiles: tile = mgroup*16 + kt  (mgroup = m/16, kt = k/64), 1KB each.
//   within tile: lane = (k%64/16)*16 + (m%16); byte j = k%16; offset lane*16+j.
// B tiles: same with p-columns: p -> gate = p&3, col = p>>2, n = gate*512+col.
__global__ __launch_bounds__(256) void prep_kernel(
    const void* __restrict__ x, const void* __restrict__ hx,
    const void* __restrict__ w_ih, const void* __restrict__ w_hh,
    int8_t* __restrict__ Xhi, int8_t* __restrict__ Xlo, int8_t* __restrict__ Bp) {
  const int isF32 = detect_f32(x);
  const long gtid = (long)blockIdx.x * 256 + threadIdx.x;
  if (gtid < 524288L) {  // X part: 8192*1024/16 threads, 16 elems each
    const int tile = (int)(gtid >> 6);
    const int lane = (int)(gtid & 63);
    const int kt = tile & 15;
    const int m = ((tile >> 4) << 4) | (lane & 15);
    const int k = kt * 64 + (lane >> 4) * 16;
    const void* src = (k < 512) ? x : hx;
    const long soff = (long)m * 512 + (k & 511);
    float v[16];
    if (isF32) {
      const float4x* s4 = (const float4x*)((const float*)src + soff);
#pragma unroll
      for (int q = 0; q < 4; ++q) {
        float4x t = s4[q];
        v[q * 4] = t[0]; v[q * 4 + 1] = t[1]; v[q * 4 + 2] = t[2]; v[q * 4 + 3] = t[3];
      }
    } else {
      const uint16_t* s = (const uint16_t*)src + soff;
#pragma unroll
      for (int j = 0; j < 16; ++j) v[j] = bf2f(s[j]);
    }
    union { int8_t b[16]; int4x v4; } uh, ul;
#pragma unroll
    for (int j = 0; j < 16; ++j) {
      float c = fminf(fmaxf(v[j], -8.0f), 8.0f);
      int xf = __float2int_rn(c * 4096.0f);
      xf = xf > 32639 ? 32639 : xf;
      xf = xf < -32768 ? -32768 : xf;
      const int lo = (xf << 24) >> 24;       // sign-extended low byte
      const int hi = (xf - lo) >> 8;         // exact: xf = hi*256 + lo
      ul.b[j] = (int8_t)lo;
      uh.b[j] = (int8_t)hi;
    }
    *(int4x*)(Xhi + (long)tile * 1024 + lane * 16) = uh.v4;
    *(int4x*)(Xlo + (long)tile * 1024 + lane * 16) = ul.v4;
  } else {  // W part: 2048*1024/16 threads
    const long g2 = gtid - 524288L;
    const int tile = (int)(g2 >> 6);
    const int lane = (int)(g2 & 63);
    const int kt = tile & 15;
    const int p = ((tile >> 4) << 4) | (lane & 15);
    const int n = (p & 3) * 512 + (p >> 2);
    const int k = kt * 64 + (lane >> 4) * 16;
    const void* src = (k < 512) ? w_ih : w_hh;
    const long soff = (long)n * 512 + (k & 511);
    union { int8_t b[16]; int4x v4; } us;
    if (isF32) {
      const float4x* s4 = (const float4x*)((const float*)src + soff);
#pragma unroll
      for (int q = 0; q < 4; ++q) {
        float4x t = s4[q];
#pragma unroll
        for (int j = 0; j < 4; ++j) {
          const float wv = t[j];
          us.b[q * 4 + j] = (int8_t)(wv > 0.f ? 1 : (wv < 0.f ? -1 : 0));
        }
      }
    } else {
      const uint16_t* s = (const uint16_t*)src + soff;
#pragma unroll
      for (int j = 0; j < 16; ++j) {
        const uint16_t u = s[j];
        us.b[j] = (int8_t)(((u & 0x7FFFu) == 0) ? 0 : ((u & 0x8000u) ? -1 : 1));
      }
    }
    *(int4x*)(Bp + (long)tile * 1024 + lane * 16) = us.v4;
  }
}

// ---------------- fused GEMM (i8 dual-pass) + LSTM epilogue ------------------------
// grid (32, 64): bx -> 64 p-cols (16 h-cols x 4 gates), by -> 128 rows.
// Tile 128x64, LDS 20KB, 4 blocks/CU resident, grid = 2 clean rounds, no tail.
__global__ __launch_bounds__(256, 4) void blstm_gemm_kernel(
    const int8_t* __restrict__ Xhi, const int8_t* __restrict__ Xlo,
    const int8_t* __restrict__ Bp, const void* __restrict__ b_ih,
    const void* __restrict__ b_hh, const void* __restrict__ cx,
    const void* __restrict__ xdet, void* __restrict__ out) {
  __shared__ alignas(16) char lds[20480];  // Ahi [0,8K) Alo [8K,16K) B [16K,20K)
  const int tid = threadIdx.x;
  const int l = tid & 63, w = tid >> 6;
  const int lrow = l & 15, lq = l >> 4;
  const int isF32 = detect_f32(xdet);
  const int bx = blockIdx.x, by = blockIdx.y;

  // 20 staging chunks (8 Ahi + 8 Alo + 4 B), 5 per wave; 1KB per wave-instr.
  const int8_t* sp[5];
  int dof[5];
#pragma unroll
  for (int i = 0; i < 5; ++i) {
    const int c = w * 5 + i;
    if (c < 8) {
      sp[i] = Xhi + ((long)(by * 8 + c) * 16) * 1024 + l * 16;
      dof[i] = c * 1024;
    } else if (c < 16) {
      sp[i] = Xlo + ((long)(by * 8 + (c - 8)) * 16) * 1024 + l * 16;
      dof[i] = 8192 + (c - 8) * 1024;
    } else {
      sp[i] = Bp + ((long)(bx * 4 + (c - 16)) * 16) * 1024 + l * 16;
      dof[i] = 16384 + (c - 16) * 1024;
    }
  }

  int4x acch[2][4], accl[2][4];
#pragma unroll
  for (int mt = 0; mt < 2; ++mt)
#pragma unroll
    for (int nt = 0; nt < 4; ++nt) {
      acch[mt][nt] = (int4x){0, 0, 0, 0};
      accl[mt][nt] = (int4x){0, 0, 0, 0};
    }

  for (int ks = 0; ks < 16; ++ks) {
    __syncthreads();
#pragma unroll
    for (int i = 0; i < 5; ++i) {
      gld_lds16(sp[i], lds + dof[i]);
      sp[i] += 1024;  // next k-tile
    }
    __syncthreads();
    int4x ah[2], al[2], b[4];
#pragma unroll
    for (int mt = 0; mt < 2; ++mt) {
      ah[mt] = *(const int4x*)(lds + (w * 2 + mt) * 1024 + l * 16);
      al[mt] = *(const int4x*)(lds + 8192 + (w * 2 + mt) * 1024 + l * 16);
    }
#pragma unroll
    for (int nt = 0; nt < 4; ++nt)
      b[nt] = *(const int4x*)(lds + 16384 + nt * 1024 + l * 16);
#pragma unroll
    for (int mt = 0; mt < 2; ++mt)
#pragma unroll
      for (int nt = 0; nt < 4; ++nt) {
        acch[mt][nt] = __builtin_amdgcn_mfma_i32_16x16x64_i8(ah[mt], b[nt], acch[mt][nt], 0, 0, 0);
        accl[mt][nt] = __builtin_amdgcn_mfma_i32_16x16x64_i8(al[mt], b[nt], accl[mt][nt], 0, 0, 0);
      }
  }

  // ---------------- epilogue: gates -> (hy, cy), all 4 gates in-wave ---------------
  const long CYo = (long)B_DIM * H_DIM;
  float biasv[4];
#pragma unroll
  for (int nt = 0; nt < 4; ++nt) {
    const int c = bx * 16 + nt * 4 + (lrow >> 2);
    const int n = (l & 3) * 512 + c;
    if (isF32)
      biasv[nt] = ((const float*)b_ih)[n] + ((const float*)b_hh)[n];
    else
      biasv[nt] = bf2f(((const uint16_t*)b_ih)[n]) + bf2f(((const uint16_t*)b_hh)[n]);
  }
  float* outF = (float*)out;
  uint16_t* outB = (uint16_t*)out;
  const int base = l & ~3;
#pragma unroll
  for (int mt = 0; mt < 2; ++mt) {
#pragma unroll
    for (int nt = 0; nt < 4; ++nt) {
      const int c = bx * 16 + nt * 4 + (lrow >> 2);
      const int rowbase = by * 128 + (w * 2 + mt) * 16 + lq * 4;
      float myi = 0.f, myf = 0.f, myg = 0.f, myo = 0.f;
#pragma unroll
      for (int r = 0; r < 4; ++r) {
        const float v = fmaf((float)acch[mt][nt][r], 0.0625f,
                             (float)accl[mt][nt][r] * (1.0f / 4096.0f)) + biasv[nt];
        const float vi = __shfl(v, base + 0, 64);
        const float vf = __shfl(v, base + 1, 64);
        const float vg = __shfl(v, base + 2, 64);
        const float vo = __shfl(v, base + 3, 64);
        if ((l & 3) == r) { myi = vi; myf = vf; myg = vg; myo = vo; }
      }
      const int row = rowbase + (l & 3);
      const long cidx = (long)row * H_DIM + c;
      const float cxv = isF32 ? ((const float*)cx)[cidx] : bf2f(((const uint16_t*)cx)[cidx]);
      const float ig = sigm(myi), fg = sigm(myf), og = sigm(myo);
      const float cg = tanh_f(myg);
      const float cy = fg * cxv + ig * cg;
      const float hy = og * tanh_f(cy);
      if (isF32) {
        outF[cidx] = hy;
        outF[CYo + cidx] = cy;
      } else {
        outB[cidx] = f2bf(hy);
        outB[CYo + cidx] = f2bf(cy);
      }
    }
  }
}

extern "C" void kernel_launch(void* const* d_in, const int* in_sizes, int n_in,
                              void* d_out, int out_size, void* d_ws, size_t ws_size,
                              hipStream_t stream) {
  const void* x = d_in[0];
  const void* hx = d_in[1];
  const void* cx = d_in[2];
  const void* W_ih = d_in[3];
  const void* W_hh = d_in[4];
  const void* b_ih = d_in[5];
  const void* b_hh = d_in[6];
  char* ws = (char*)d_ws;
  int8_t* Xhi = (int8_t*)ws;                   // 8 MB
  int8_t* Xlo = (int8_t*)(ws + 8388608);       // 8 MB
  int8_t* Bp = (int8_t*)(ws + 16777216);       // 2 MB

  prep_kernel<<<2560, 256, 0, stream>>>(x, hx, W_ih, W_hh, Xhi, Xlo, Bp);
  dim3 grid(32, 64);
  blstm_gemm_kernel<<<grid, 256, 0, stream>>>(Xhi, Xlo, Bp, b_ih, b_hh, cx, x, d_out);
}